// Round 11
// baseline (294.491 us; speedup 1.0000x reference)
//
#include <hip/hip_runtime.h>
#include <stdint.h>

#define SEQ 256
#define BATCH 32
#define IN_DIM 1024
#define HID 64
#define NPAD 1280
#define ROWS (SEQ*BATCH)   // 8192

// workspace layout (high-water 61,477,888 B — same as proven R3..R10 footprint):
//  [0,16.78M)        Xbf (prep->gemm)  then Ypk (pack->chunk kernels)  [8192*456*4 = 14.94 MB]
//  [16.78M,19.40M)   Wbf
//  [19.40M,19.40M+5K) bb
//  GATE
//  [19.53M,61.48M)   Y (gemm->pack)    then DM (37.75 MB, accum/prefix/scan)
#define XBF_OFF   0
#define YPK_OFF   0
#define WBF_OFF   16777216
#define BB_OFF    19398656
#define GATE_OFF  19403776
#define Y_OFF     19534848
#define DM_OFF    19534848

#define NC 8
#define CHL 32      // chunk length = SEQ/NC
#define NTILE 4     // CHL/8

// packed per-row record (456-float rows, floats 0..451 used):
// [k0(64) | ka(64) | kb(64) | v0(64) | va(64) | vb(64) | q(64) | gate(4)]
#define PKROW 456
#define TROW 452
#define TILEF (8*TROW)   // x2 buffers = 28,928 B LDS

typedef __attribute__((ext_vector_type(8))) short short8;
typedef __attribute__((ext_vector_type(4))) float floatx4;

// async global->LDS DMA, 16B per lane, dest = wave-uniform base + lane*16
typedef const __attribute__((address_space(1))) unsigned int gas_u32;
typedef __attribute__((address_space(3))) unsigned int las_u32;
static __device__ __forceinline__ void gl_lds16(const void* g, void* l) {
  __builtin_amdgcn_global_load_lds((gas_u32*)g, (las_u32*)l, 16, 0, 0);
}

static __device__ __forceinline__ short f2bf(float f) {
  union { float f; uint32_t u; } a; a.f = f;
  uint32_t r = (a.u + 0x7FFFu + ((a.u >> 16) & 1u)) >> 16;  // RNE
  return (short)r;
}

// ---------------- prep: fp32 -> bf16 for X, concat+convert weights, concat bias ----------------
__global__ void prep_kernel(const float* __restrict__ X,
                            const float* __restrict__ Wk, const float* __restrict__ bk,
                            const float* __restrict__ Wv, const float* __restrict__ bv,
                            const float* __restrict__ Wg, const float* __restrict__ bg,
                            const float* __restrict__ Wq, const float* __restrict__ bq,
                            short* __restrict__ Xbf, short* __restrict__ Wbf,
                            float* __restrict__ bb)
{
  int64_t idx = (int64_t)blockIdx.x * blockDim.x + threadIdx.x;
  int64_t stride = (int64_t)gridDim.x * blockDim.x;
  const int64_t NX4 = (int64_t)ROWS * IN_DIM / 4;
  for (int64_t i = idx; i < NX4; i += stride) {
    float4 x = ((const float4*)X)[i];
    short4 s4;
    s4.x = f2bf(x.x); s4.y = f2bf(x.y); s4.z = f2bf(x.z); s4.w = f2bf(x.w);
    ((short4*)Xbf)[i] = s4;
  }
  const int64_t NW4 = (int64_t)NPAD * IN_DIM / 4;
  for (int64_t i = idx; i < NW4; i += stride) {
    int64_t e = i * 4;
    int r = (int)(e >> 10);
    int k = (int)(e & 1023);
    float4 x;
    if (r < 576)       x = *(const float4*)(Wk + (int64_t)r*1024 + k);
    else if (r < 1152) x = *(const float4*)(Wv + (int64_t)(r-576)*1024 + k);
    else if (r < 1216) x = *(const float4*)(Wq + (int64_t)(r-1152)*1024 + k);
    else               x = make_float4(0.f, 0.f, 0.f, 0.f);
    short4 s4;
    s4.x = f2bf(x.x); s4.y = f2bf(x.y); s4.z = f2bf(x.z); s4.w = f2bf(x.w);
    ((short4*)Wbf)[i] = s4;
  }
  for (int64_t i = idx; i < NPAD; i += stride) {
    int r = (int)i; float v;
    if (r < 576)       v = bk[r];
    else if (r < 1152) v = bv[r - 576];
    else if (r < 1216) v = bq[r - 1152];
    else               v = 0.f;
    bb[r] = v;
  }
}

// ---------------- GEMM: Y[8192,1280] = Xbf @ Wbf^T + bb ----------------
__global__ __launch_bounds__(256) void gemm_kernel(
    const short* __restrict__ Xbf,
    const short* __restrict__ Wbf,
    const float* __restrict__ bb,
    float* __restrict__ Y)
{
  __shared__ short As[128 * 32];   // 8 KB
  __shared__ short Bs[128 * 32];   // 8 KB

  const int tid  = threadIdx.x;
  const int lane = tid & 63;
  const int wv   = tid >> 6;
  const int quad = lane >> 4;
  const int cl   = lane & 15;
  const int wm   = wv & 1;
  const int wn   = wv >> 1;
  const int m0 = blockIdx.y * 128;
  const int n0 = blockIdx.x * 128;

  const int srow = wv * 32 + (lane >> 2);
  const int scol = (lane & 3) * 8;
  const short* gA = Xbf + (int64_t)(m0 + srow) * IN_DIM + scol;
  const short* gB = Wbf + (int64_t)(n0 + srow) * IN_DIM + scol;
  short* lA = As + (wv * 32) * 32;
  short* lB = Bs + (wv * 32) * 32;

  floatx4 acc[4][4];
#pragma unroll
  for (int i = 0; i < 4; i++)
#pragma unroll
    for (int k = 0; k < 4; k++) acc[i][k] = (floatx4){0.f, 0.f, 0.f, 0.f};

  for (int ks = 0; ks < IN_DIM; ks += 32) {
    gl_lds16(gA + ks,                lA);
    gl_lds16(gA + 16 * IN_DIM + ks,  lA + 16 * 32);
    gl_lds16(gB + ks,                lB);
    gl_lds16(gB + 16 * IN_DIM + ks,  lB + 16 * 32);
    __syncthreads();

    short8 bfrag[4], afrag[4];
#pragma unroll
    for (int nt = 0; nt < 4; nt++)
      bfrag[nt] = *(const short8*)(&Bs[(wn * 64 + nt * 16 + cl) * 32 + quad * 8]);
#pragma unroll
    for (int mt = 0; mt < 4; mt++)
      afrag[mt] = *(const short8*)(&As[(wm * 64 + mt * 16 + cl) * 32 + quad * 8]);
#pragma unroll
    for (int mt = 0; mt < 4; mt++)
#pragma unroll
      for (int nt = 0; nt < 4; nt++)
        acc[mt][nt] = __builtin_amdgcn_mfma_f32_16x16x32_bf16(afrag[mt], bfrag[nt], acc[mt][nt], 0, 0, 0);
    __syncthreads();
  }

#pragma unroll
  for (int nt = 0; nt < 4; nt++) {
    const int col = n0 + wn * 64 + nt * 16 + cl;
    const float bias = bb[col];
#pragma unroll
    for (int mt = 0; mt < 4; mt++) {
#pragma unroll
      for (int r = 0; r < 4; r++) {
        int row = m0 + wm * 64 + mt * 16 + quad * 4 + r;
        Y[(int64_t)row * NPAD + col] = acc[mt][nt][r] + bias;
      }
    }
  }
}

// ---------------- gate (fp32-exact): logits from X,Wg; top-2 + renormalized weights ----------------
__global__ __launch_bounds__(256) void gate_kernel(
    const float* __restrict__ X,
    const float* __restrict__ Wg, const float* __restrict__ bg,
    float4* __restrict__ gate)
{
  const int lane = threadIdx.x & 63;
  const int row  = blockIdx.x * 4 + (threadIdx.x >> 6);
  const float* x = X + (int64_t)row * IN_DIM;

  float acc[8];
#pragma unroll
  for (int e = 0; e < 8; e++) acc[e] = 0.f;

#pragma unroll
  for (int i = 0; i < 4; i++) {
    const int off = i * 256 + lane * 4;
    float4 xv = *(const float4*)(x + off);
#pragma unroll
    for (int e = 0; e < 8; e++) {
      float4 wv = *(const float4*)(Wg + e * IN_DIM + off);
      acc[e] += xv.x * wv.x + xv.y * wv.y + xv.z * wv.z + xv.w * wv.w;
    }
  }
#pragma unroll
  for (int e = 0; e < 8; e++) {
#pragma unroll
    for (int m = 32; m >= 1; m >>= 1)
      acc[e] += __shfl_xor(acc[e], m);
    acc[e] += bg[e];
  }

  if (lane == 0) {
    int i0 = 0; float v0 = acc[0];
#pragma unroll
    for (int e = 1; e < 8; e++) if (acc[e] > v0) { v0 = acc[e]; i0 = e; }
    int i1 = -1; float v1 = -3.4e38f;
#pragma unroll
    for (int e = 0; e < 8; e++) if (e != i0 && acc[e] > v1) { v1 = acc[e]; i1 = e; }
    float e1 = __expf(v1 - v0);
    float inv = 1.f / (1.f + e1);
    gate[row] = make_float4(__int_as_float(i0), __int_as_float(i1), inv, e1 * inv);
  }
}

// ---------------- pack: gather gate-routed segments -> compact Ypk rows ----------------
// One wave per row, 8192 independent waves (latency-immune scattered gather, paid once).
__global__ __launch_bounds__(256) void pack_kernel(
    const float* __restrict__ Y, const float4* __restrict__ gate,
    float* __restrict__ Ypk)
{
  const int row  = blockIdx.x * 4 + (threadIdx.x >> 6);   // r = t*BATCH+b
  const int lane = threadIdx.x & 63;
  const float* Yp = Y + (int64_t)row * NPAD;
  float* Pp = Ypk + (int64_t)row * PKROW;
  float4 g = gate[row];
  const int i0 = __float_as_int(g.x), i1 = __float_as_int(g.y);

#define PSRC(IDX) ({                                                 \
    const int seg = (IDX) >> 4;                                      \
    const int off = ((IDX) & 15) * 4;                                \
    const int base = (seg == 6) ? 1152 : ((seg >= 3) ? 576 : 0);     \
    const int s3 = (seg >= 3 && seg < 6) ? seg - 3 : seg;            \
    const int slot = (s3 == 1) ? i0 * 64 : ((s3 == 2) ? i1 * 64 : 0);\
    (const float4*)(Yp + base + slot + off); })

  float4 r0 = *PSRC(lane);                       // idx 0..63 (k0,ka,kb,v0)
  float4 r1;
  if (lane < 48) r1 = *PSRC(64 + lane);          // idx 64..111 (va,vb,q)
  *(float4*)(Pp + lane * 4) = r0;
  if (lane < 48) *(float4*)(Pp + (64 + lane) * 4) = r1;
  if (lane == 48) *(float4*)(Pp + 448) = g;      // idx 112 = gate
#undef PSRC
}

// 16-lane (DPP row) sum; result valid in lane (lane&15)==15 of each row.
static __device__ __forceinline__ float row16_sum(float x) {
  float r = x;
  r += __int_as_float(__builtin_amdgcn_update_dpp(0, __float_as_int(r), 0x118, 0xf, 0xf, false)); // row_shr:8
  r += __int_as_float(__builtin_amdgcn_update_dpp(0, __float_as_int(r), 0x114, 0xf, 0xf, false)); // row_shr:4
  r += __int_as_float(__builtin_amdgcn_update_dpp(0, __float_as_int(r), 0x112, 0xf, 0xf, false)); // row_shr:2
  r += __int_as_float(__builtin_amdgcn_update_dpp(0, __float_as_int(r), 0x111, 0xf, 0xf, false)); // row_shr:1
  return r;
}

// ======================= chunked scan — BRANCHLESS compute =======================
// R10 post-mortem: per-step cost ~1270 cyc/CU across three staging schemes ->
// bottleneck is the wave-uniform switch structure (branch boundaries kill
// inter-step pipelining). Branchless: routed slots are raw m_idx in [0,8)
// (slot 8 is NEVER updated by the reference); update = masked FMA over m<8,
// readout weight rw[m] = d(m,0) + g0*d(m,i0) + g1*d(m,i1) applied post-update
// (exact reference semantics, no slot-0 special case needed). ~120 VALU/step,
// dep chain ~2 FMA/step, fully pipelineable. nc=8 (compact Ypk + DM overlay
// keep ws high-water at the proven 61.5 MB) -> 1024 blocks = 4/CU.

#define STAGE_TILE(TBASE, DST) {                                     \
    const int trow = (TBASE) + srow_;                                \
    const float* Yp = Ypk + (int64_t)(trow * BATCH + b) * PKROW;     \
    float* dbuf = sY + (DST) * TILEF + srow_ * TROW;                 \
    _Pragma("unroll")                                                \
    for (int k = 0; k < 4; k++) {                                    \
      const int idx = rtid_ + 32 * k;                                \
      if (idx < 113)                                                 \
        *(float4*)(dbuf + idx * 4) = *(const float4*)(Yp + idx * 4); \
    } }

// ---------------- phase A: per-chunk delta accumulation ----------------
__global__ __launch_bounds__(256) void chunk_accum_kernel(
    const float* __restrict__ Ypk, float* __restrict__ DM)
{
  __shared__ float sY[2 * TILEF];
  const int blk  = blockIdx.x;
  const int c    = blk & 7;
  const int rest = blk >> 3;
  const int jblk = rest & 3;
  const int b    = rest >> 2;
  const int tid  = threadIdx.x;
  const int lane = tid & 63;
  const int wv   = tid >> 6;
  const int igrp = lane & 15;
  const int jloc = lane >> 4;
  const int j    = jblk * 16 + wv * 4 + jloc;
  const int ib   = igrp * 4;
  const int srow_ = tid >> 5;
  const int rtid_ = tid & 31;
  const int t0   = c * CHL;

  float D[9][4];
#pragma unroll
  for (int m = 0; m < 9; m++)
#pragma unroll
    for (int ii = 0; ii < 4; ii++) D[m][ii] = 0.f;

#define CSTEP_A(P, R) {                                              \
    const float* rb = sY + (P) * TILEF + (R) * TROW;                 \
    float4 gl = *(const float4*)(rb + 448);                          \
    float4 k0 = *(const float4*)(rb + ib);                           \
    float4 ka = *(const float4*)(rb + 64 + ib);                      \
    float4 kb = *(const float4*)(rb + 128 + ib);                     \
    float v0 = rb[192 + j];                                          \
    float va = rb[256 + j];                                          \
    float vb = rb[320 + j];                                          \
    const int iA = __float_as_int(gl.x);                             \
    const int iB = __float_as_int(gl.y);                             \
    float pa0 = ka.x*va, pa1 = ka.y*va, pa2 = ka.z*va, pa3 = ka.w*va;\
    float pb0 = kb.x*vb, pb1 = kb.y*vb, pb2 = kb.z*vb, pb3 = kb.w*vb;\
    D[0][0] += k0.x*v0; D[0][1] += k0.y*v0;                          \
    D[0][2] += k0.z*v0; D[0][3] += k0.w*v0;                          \
    _Pragma("unroll")                                                \
    for (int m = 0; m < 8; m++) {                                    \
      float wa = (iA == m) ? 1.f : 0.f;                              \
      float wb = (iB == m) ? 1.f : 0.f;                              \
      D[m][0] += wa*pa0 + wb*pb0;                                    \
      D[m][1] += wa*pa1 + wb*pb1;                                    \
      D[m][2] += wa*pa2 + wb*pb2;                                    \
      D[m][3] += wa*pa3 + wb*pb3;                                    \
    } }

  STAGE_TILE(t0, 0);

  for (int tile = 0; tile < NTILE; ++tile) {
    const int p = tile & 1;
    __syncthreads();
#pragma unroll
    for (int r = 0; r < 8; r++) CSTEP_A(p, r);
    if (tile + 1 < NTILE) STAGE_TILE(t0 + (tile + 1) * 8, p ^ 1);
  }
#undef CSTEP_A

  float* dmb = DM + ((int64_t)(c * 32 + b)) * 36864;
#pragma unroll
  for (int m = 0; m < 9; m++)
#pragma unroll
    for (int ii = 0; ii < 4; ii++)
      dmb[m * 4096 + (ib + ii) * 64 + j] = D[m][ii];
}

// ---------------- phase B: in-place exclusive prefix (+M0) over chunks ----------------
__global__ void prefix_kernel(const float* __restrict__ M0, float* __restrict__ DM, int nc)
{
  int64_t e = (int64_t)blockIdx.x * blockDim.x + threadIdx.x;   // < 32*36864
  int b = (int)(e / 36864);
  int r = (int)(e % 36864);
  float run = M0[e];
  for (int cc = 0; cc < nc; cc++) {
    int64_t idx = ((int64_t)(cc * 32 + b)) * 36864 + r;
    float tmp = DM[idx];
    DM[idx] = run;
    run += tmp;
  }
}

// ---------------- phase C: intra-chunk recurrence + readout ----------------
__global__ __launch_bounds__(256) void chunk_scan_kernel(
    const float* __restrict__ Ypk,
    const float* __restrict__ DM,   // holds Mstart(c) after prefix
    float* __restrict__ out)
{
  __shared__ float sY[2 * TILEF];
  const int blk  = blockIdx.x;
  const int c    = blk & 7;
  const int rest = blk >> 3;
  const int jblk = rest & 3;
  const int b    = rest >> 2;
  const int tid  = threadIdx.x;
  const int lane = tid & 63;
  const int wv   = tid >> 6;
  const int igrp = lane & 15;
  const int jloc = lane >> 4;
  const int j    = jblk * 16 + wv * 4 + jloc;
  const int ib   = igrp * 4;
  const int srow_ = tid >> 5;
  const int rtid_ = tid & 31;
  const int t0   = c * CHL;

  float M[9][4];
  const float* msb = DM + ((int64_t)(c * 32 + b)) * 36864;
#pragma unroll
  for (int m = 0; m < 9; m++)
#pragma unroll
    for (int ii = 0; ii < 4; ii++)
      M[m][ii] = msb[m * 4096 + (ib + ii) * 64 + j];

#define CSTEP_C(P, R, TT) {                                          \
    const float* rb = sY + (P) * TILEF + (R) * TROW;                 \
    float4 gl = *(const float4*)(rb + 448);                          \
    float4 k0 = *(const float4*)(rb + ib);                           \
    float4 ka = *(const float4*)(rb + 64 + ib);                      \
    float4 kb = *(const float4*)(rb + 128 + ib);                     \
    float v0 = rb[192 + j];                                          \
    float va = rb[256 + j];                                          \
    float vb = rb[320 + j];                                          \
    float4 qv = *(const float4*)(rb + 384 + ib);                     \
    const int iA = __float_as_int(gl.x);                             \
    const int iB = __float_as_int(gl.y);                             \
    const float g0w = gl.z, g1w = gl.w;                              \
    float pa0 = ka.x*va, pa1 = ka.y*va, pa2 = ka.z*va, pa3 = ka.w*va;\
    float pb0 = kb.x*vb, pb1 = kb.y*vb, pb2 = kb.z*vb, pb3 = kb.w*vb;\
    M[0][0] += k0.x*v0; M[0][1] += k0.y*v0;                          \
    M[0][2] += k0.z*v0; M[0][3] += k0.w*v0;                          \
    float Mc0 = 0.f, Mc1 = 0.f, Mc2 = 0.f, Mc3 = 0.f;                \
    _Pragma("unroll")                                                \
    for (int m = 0; m < 8; m++) {                                    \
      float wa = (iA == m) ? 1.f : 0.f;                              \
      float wb = (iB == m) ? 1.f : 0.f;                              \
      M[m][0] += wa*pa0 + wb*pb0;                                    \
      M[m][1] += wa*pa1 + wb*pb1;                                    \
      M[m][2] += wa*pa2 + wb*pb2;                                    \
      M[m][3] += wa*pa3 + wb*pb3;                                    \
      float rw = ((m == 0) ? 1.f : 0.f) + g0w*wa + g1w*wb;           \
      Mc0 += rw*M[m][0]; Mc1 += rw*M[m][1];                          \
      Mc2 += rw*M[m][2]; Mc3 += rw*M[m][3];                          \
    }                                                                \
    float part = qv.x*Mc0 + qv.y*Mc1 + qv.z*Mc2 + qv.w*Mc3;          \
    part = row16_sum(part);                                          \
    if (igrp == 15)                                                  \
      out[(int64_t)(TT) * (BATCH * HID) + b * HID + j] = part; }

  STAGE_TILE(t0, 0);

  for (int tile = 0; tile < NTILE; ++tile) {
    const int p = tile & 1;
    __syncthreads();
#pragma unroll
    for (int r = 0; r < 8; r++) CSTEP_C(p, r, t0 + tile * 8 + r);
    if (tile + 1 < NTILE) STAGE_TILE(t0 + (tile + 1) * 8, p ^ 1);
  }
#undef CSTEP_C

  if (c == 7) {   // last chunk owns M_final
    float* Mf = out + (int64_t)SEQ * BATCH * HID + (int64_t)b * 36864;
#pragma unroll
    for (int m = 0; m < 9; m++)
#pragma unroll
      for (int ii = 0; ii < 4; ii++)
        Mf[m * 4096 + (ib + ii) * 64 + j] = M[m][ii];
  }
}

// ---------------- launch ----------------
extern "C" void kernel_launch(void* const* d_in, const int* in_sizes, int n_in,
                              void* d_out, int out_size, void* d_ws, size_t ws_size,
                              hipStream_t stream)
{
  const float* X  = (const float*)d_in[0];
  const float* M0 = (const float*)d_in[1];
  const float* Wk = (const float*)d_in[2];
  const float* bk = (const float*)d_in[3];
  const float* Wv = (const float*)d_in[4];
  const float* bv = (const float*)d_in[5];
  const float* Wg = (const float*)d_in[6];
  const float* bg = (const float*)d_in[7];
  const float* Wq = (const float*)d_in[8];
  const float* bq = (const float*)d_in[9];

  char* ws = (char*)d_ws;
  short*  Xbf  = (short*)(ws + XBF_OFF);
  short*  Wbf  = (short*)(ws + WBF_OFF);
  float*  bb   = (float*)(ws + BB_OFF);
  float4* gate = (float4*)(ws + GATE_OFF);
  float*  Y    = (float*)(ws + Y_OFF);
  float*  Ypk  = (float*)(ws + YPK_OFF);   // overlays Xbf (dead after gemm)
  float*  DM   = (float*)(ws + DM_OFF);    // overlays Y   (dead after pack)
  float*  out  = (float*)d_out;

  prep_kernel<<<2048, 256, 0, stream>>>(X, Wk, bk, Wv, bv, Wg, bg, Wq, bq, Xbf, Wbf, bb);
  gate_kernel<<<ROWS / 4, 256, 0, stream>>>(X, Wg, bg, gate);
  dim3 gg(NPAD / 128, ROWS / 128);
  gemm_kernel<<<gg, 256, 0, stream>>>(Xbf, Wbf, bb, Y);
  pack_kernel<<<ROWS / 4, 256, 0, stream>>>(Y, gate, Ypk);
  chunk_accum_kernel<<<32 * NC * 4, 256, 0, stream>>>(Ypk, DM);
  prefix_kernel<<<(32 * 36864) / 256, 256, 0, stream>>>(M0, DM, NC);
  chunk_scan_kernel<<<32 * NC * 4, 256, 0, stream>>>(Ypk, DM, out);
}

// Round 13
// 245.938 us; speedup vs baseline: 1.1974x; 1.1974x over previous
//
#include <hip/hip_runtime.h>
#include <stdint.h>

#define SEQ 256
#define BATCH 32
#define IN_DIM 1024
#define HID 64
#define NPAD 1280
#define ROWS (SEQ*BATCH)   // 8192

// workspace layout (high-water 61,477,888 B — proven footprint):
//  [0,16.78M)   Xbf (prep->gemm) then Ypk bf16-packed (pack->chunks) [8192*928B = 7.6 MB]
//  [16.78M,..)  Wbf, bb, gate
//  [19.53M,61.48M) Y (gemm->pack) then DM (37.75 MB)
#define XBF_OFF   0
#define YPK_OFF   0
#define WBF_OFF   16777216
#define BB_OFF    19398656
#define GATE_OFF  19403776
#define Y_OFF     19534848
#define DM_OFF    19534848

#define NC 8
#define CHL 32      // chunk length
#define NTILE 4     // CHL/8

// packed bf16 record, 232 dwords (928 B)/row:
// ushorts: k0[64]@0 | ka@64 | kb@128 | q@192 | v0@256 | va@320 | vb@384 | gate(4 fp32 raw)@448
// dwords:  k0@0..31 | ka@32 | kb@64 | q@96 | v0@128 | va@160 | vb@192 | gate@224
#define PKROW_D 232
#define TROW_D  232
#define TILEF_D (8*TROW_D)   // 1856 dwords/buffer; x2 = 14,848 B LDS

typedef __attribute__((ext_vector_type(8))) short short8;
typedef __attribute__((ext_vector_type(4))) float floatx4;

typedef const __attribute__((address_space(1))) unsigned int gas_u32;
typedef __attribute__((address_space(3))) unsigned int las_u32;
static __device__ __forceinline__ void gl_lds16(const void* g, void* l) {
  __builtin_amdgcn_global_load_lds((gas_u32*)g, (las_u32*)l, 16, 0, 0);
}

static __device__ __forceinline__ short f2bf(float f) {
  union { float f; uint32_t u; } a; a.f = f;
  uint32_t r = (a.u + 0x7FFFu + ((a.u >> 16) & 1u)) >> 16;  // RNE
  return (short)r;
}
static __device__ __forceinline__ float bflo(uint32_t u){ return __uint_as_float(u << 16); }
static __device__ __forceinline__ float bfhi(uint32_t u){ return __uint_as_float(u & 0xffff0000u); }

// ---------------- prep ----------------
__global__ void prep_kernel(const float* __restrict__ X,
                            const float* __restrict__ Wk, const float* __restrict__ bk,
                            const float* __restrict__ Wv, const float* __restrict__ bv,
                            const float* __restrict__ Wg, const float* __restrict__ bg,
                            const float* __restrict__ Wq, const float* __restrict__ bq,
                            short* __restrict__ Xbf, short* __restrict__ Wbf,
                            float* __restrict__ bb)
{
  int64_t idx = (int64_t)blockIdx.x * blockDim.x + threadIdx.x;
  int64_t stride = (int64_t)gridDim.x * blockDim.x;
  const int64_t NX4 = (int64_t)ROWS * IN_DIM / 4;
  for (int64_t i = idx; i < NX4; i += stride) {
    float4 x = ((const float4*)X)[i];
    short4 s4;
    s4.x = f2bf(x.x); s4.y = f2bf(x.y); s4.z = f2bf(x.z); s4.w = f2bf(x.w);
    ((short4*)Xbf)[i] = s4;
  }
  const int64_t NW4 = (int64_t)NPAD * IN_DIM / 4;
  for (int64_t i = idx; i < NW4; i += stride) {
    int64_t e = i * 4;
    int r = (int)(e >> 10);
    int k = (int)(e & 1023);
    float4 x;
    if (r < 576)       x = *(const float4*)(Wk + (int64_t)r*1024 + k);
    else if (r < 1152) x = *(const float4*)(Wv + (int64_t)(r-576)*1024 + k);
    else if (r < 1216) x = *(const float4*)(Wq + (int64_t)(r-1152)*1024 + k);
    else               x = make_float4(0.f, 0.f, 0.f, 0.f);
    short4 s4;
    s4.x = f2bf(x.x); s4.y = f2bf(x.y); s4.z = f2bf(x.z); s4.w = f2bf(x.w);
    ((short4*)Wbf)[i] = s4;
  }
  for (int64_t i = idx; i < NPAD; i += stride) {
    int r = (int)i; float v;
    if (r < 576)       v = bk[r];
    else if (r < 1152) v = bv[r - 576];
    else if (r < 1216) v = bq[r - 1152];
    else               v = 0.f;
    bb[r] = v;
  }
}

// ---------------- GEMM ----------------
__global__ __launch_bounds__(256) void gemm_kernel(
    const short* __restrict__ Xbf,
    const short* __restrict__ Wbf,
    const float* __restrict__ bb,
    float* __restrict__ Y)
{
  __shared__ short As[128 * 32];
  __shared__ short Bs[128 * 32];

  const int tid  = threadIdx.x;
  const int lane = tid & 63;
  const int wv   = tid >> 6;
  const int quad = lane >> 4;
  const int cl   = lane & 15;
  const int wm   = wv & 1;
  const int wn   = wv >> 1;
  const int m0 = blockIdx.y * 128;
  const int n0 = blockIdx.x * 128;

  const int srow = wv * 32 + (lane >> 2);
  const int scol = (lane & 3) * 8;
  const short* gA = Xbf + (int64_t)(m0 + srow) * IN_DIM + scol;
  const short* gB = Wbf + (int64_t)(n0 + srow) * IN_DIM + scol;
  short* lA = As + (wv * 32) * 32;
  short* lB = Bs + (wv * 32) * 32;

  floatx4 acc[4][4];
#pragma unroll
  for (int i = 0; i < 4; i++)
#pragma unroll
    for (int k = 0; k < 4; k++) acc[i][k] = (floatx4){0.f, 0.f, 0.f, 0.f};

  for (int ks = 0; ks < IN_DIM; ks += 32) {
    gl_lds16(gA + ks,                lA);
    gl_lds16(gA + 16 * IN_DIM + ks,  lA + 16 * 32);
    gl_lds16(gB + ks,                lB);
    gl_lds16(gB + 16 * IN_DIM + ks,  lB + 16 * 32);
    __syncthreads();

    short8 bfrag[4], afrag[4];
#pragma unroll
    for (int nt = 0; nt < 4; nt++)
      bfrag[nt] = *(const short8*)(&Bs[(wn * 64 + nt * 16 + cl) * 32 + quad * 8]);
#pragma unroll
    for (int mt = 0; mt < 4; mt++)
      afrag[mt] = *(const short8*)(&As[(wm * 64 + mt * 16 + cl) * 32 + quad * 8]);
#pragma unroll
    for (int mt = 0; mt < 4; mt++)
#pragma unroll
      for (int nt = 0; nt < 4; nt++)
        acc[mt][nt] = __builtin_amdgcn_mfma_f32_16x16x32_bf16(afrag[mt], bfrag[nt], acc[mt][nt], 0, 0, 0);
    __syncthreads();
  }

#pragma unroll
  for (int nt = 0; nt < 4; nt++) {
    const int col = n0 + wn * 64 + nt * 16 + cl;
    const float bias = bb[col];
#pragma unroll
    for (int mt = 0; mt < 4; mt++) {
#pragma unroll
      for (int r = 0; r < 4; r++) {
        int row = m0 + wm * 64 + mt * 16 + quad * 4 + r;
        Y[(int64_t)row * NPAD + col] = acc[mt][nt][r] + bias;
      }
    }
  }
}

// ---------------- gate (fp32-exact) ----------------
__global__ __launch_bounds__(256) void gate_kernel(
    const float* __restrict__ X,
    const float* __restrict__ Wg, const float* __restrict__ bg,
    float4* __restrict__ gate)
{
  const int lane = threadIdx.x & 63;
  const int row  = blockIdx.x * 4 + (threadIdx.x >> 6);
  const float* x = X + (int64_t)row * IN_DIM;

  float acc[8];
#pragma unroll
  for (int e = 0; e < 8; e++) acc[e] = 0.f;

#pragma unroll
  for (int i = 0; i < 4; i++) {
    const int off = i * 256 + lane * 4;
    float4 xv = *(const float4*)(x + off);
#pragma unroll
    for (int e = 0; e < 8; e++) {
      float4 wv = *(const float4*)(Wg + e * IN_DIM + off);
      acc[e] += xv.x * wv.x + xv.y * wv.y + xv.z * wv.z + xv.w * wv.w;
    }
  }
#pragma unroll
  for (int e = 0; e < 8; e++) {
#pragma unroll
    for (int m = 32; m >= 1; m >>= 1)
      acc[e] += __shfl_xor(acc[e], m);
    acc[e] += bg[e];
  }

  if (lane == 0) {
    int i0 = 0; float v0 = acc[0];
#pragma unroll
    for (int e = 1; e < 8; e++) if (acc[e] > v0) { v0 = acc[e]; i0 = e; }
    int i1 = -1; float v1 = -3.4e38f;
#pragma unroll
    for (int e = 0; e < 8; e++) if (e != i0 && acc[e] > v1) { v1 = acc[e]; i1 = e; }
    float e1 = __expf(v1 - v0);
    float inv = 1.f / (1.f + e1);
    gate[row] = make_float4(__int_as_float(i0), __int_as_float(i1), inv, e1 * inv);
  }
}

// ---------------- pack: gather + bf16-compress into 928B records ----------------
__global__ __launch_bounds__(256) void pack_kernel(
    const float* __restrict__ Y, const float4* __restrict__ gate,
    uint32_t* __restrict__ Ypk)
{
  const int row  = blockIdx.x * 4 + (threadIdx.x >> 6);
  const int lane = threadIdx.x & 63;
  const float* Yp = Y + (int64_t)row * NPAD;
  uint32_t* Pp = Ypk + (int64_t)row * PKROW_D;
  float4 g = gate[row];
  const int i0 = __float_as_int(g.x), i1 = __float_as_int(g.y);

  if (lane < 56) {
    const int seg = lane >> 3;          // 0:k0 1:ka 2:kb 3:q 4:v0 5:va 6:vb
    const int f0  = (lane & 7) * 8;
    const int slot = (seg == 1 || seg == 5) ? i0 : ((seg == 2 || seg == 6) ? i1 : 0);
    const int base = (seg == 3) ? 1152 : (((seg >= 4) ? 576 : 0) + 64 * slot);
    float4 a = *(const float4*)(Yp + base + f0);
    float4 bq4 = *(const float4*)(Yp + base + f0 + 4);
    short8 s;
    s[0]=f2bf(a.x); s[1]=f2bf(a.y); s[2]=f2bf(a.z); s[3]=f2bf(a.w);
    s[4]=f2bf(bq4.x); s[5]=f2bf(bq4.y); s[6]=f2bf(bq4.z); s[7]=f2bf(bq4.w);
    *(short8*)(Pp + lane * 4) = s;
  } else if (lane == 56) {
    *(float4*)(Pp + 224) = g;           // gate fp32 raw @ dword 224
  }
}

// 16-lane (DPP row) sum; result valid in lane (lane&15)==15.
static __device__ __forceinline__ float row16_sum(float x) {
  float r = x;
  r += __int_as_float(__builtin_amdgcn_update_dpp(0, __float_as_int(r), 0x118, 0xf, 0xf, false));
  r += __int_as_float(__builtin_amdgcn_update_dpp(0, __float_as_int(r), 0x114, 0xf, 0xf, false));
  r += __int_as_float(__builtin_amdgcn_update_dpp(0, __float_as_int(r), 0x112, 0xf, 0xf, false));
  r += __int_as_float(__builtin_amdgcn_update_dpp(0, __float_as_int(r), 0x111, 0xf, 0xf, false));
  return r;
}

// ======================= chunked scan — bf16 tiles, switch compute, 2 j/thread =======================
// R12 post-mortem: v-unpack dword index omitted the jblk offset — jblk=1 blocks
// consumed jblk=0's v (absmax 380). Fix: element j0=jblk*32+jp*2 lives in dword
// (seg_base + jblk*16 + jp) = seg_base + jv. Everything else identical to R12.

#define STAGE_TILE(TBASE, DST) {                                     \
    const int trow = (TBASE) + srow_;                                \
    const uint32_t* Pp = Ypk + (int64_t)(trow * BATCH + b) * PKROW_D;\
    uint32_t* dbuf = sY + (DST) * TILEF_D + srow_ * TROW_D;          \
    _Pragma("unroll")                                                \
    for (int kq = 0; kq < 2; kq++) {                                 \
      const int idx = rtid_ + 32 * kq;                               \
      if (idx < 57)                                                  \
        *(uint4*)(dbuf + idx * 4) = *(const uint4*)(Pp + idx * 4);   \
    } }

#define UNPACK_STEP_COMMON                                           \
    float4 gl = *(const float4*)(rb + 224);                          \
    uint2 uk0 = *(const uint2*)(rb + igrp * 2);                      \
    uint2 uka = *(const uint2*)(rb + 32 + igrp * 2);                 \
    uint2 ukb = *(const uint2*)(rb + 64 + igrp * 2);                 \
    uint32_t pv0 = rb[128 + jv], pva = rb[160 + jv], pvb = rb[192 + jv]; \
    const int i0 = __float_as_int(gl.x);                             \
    const int i1 = __float_as_int(gl.y);                             \
    float k00=bflo(uk0.x),k01=bfhi(uk0.x),k02=bflo(uk0.y),k03=bfhi(uk0.y); \
    float ka0=bflo(uka.x),ka1=bfhi(uka.x),ka2=bflo(uka.y),ka3=bfhi(uka.y); \
    float kb0=bflo(ukb.x),kb1=bfhi(ukb.x),kb2=bflo(ukb.y),kb3=bfhi(ukb.y); \
    float v0a=bflo(pv0), v0b=bfhi(pv0);                              \
    float vaa=bflo(pva), vab=bfhi(pva);                              \
    float vba=bflo(pvb), vbb=bfhi(pvb);

// ---------------- phase A: per-chunk delta accumulation ----------------
__global__ __launch_bounds__(256) void chunk_accum_kernel(
    const uint32_t* __restrict__ Ypk, float* __restrict__ DM)
{
  __shared__ uint32_t sY[2 * TILEF_D];
  const int blk  = blockIdx.x;
  const int c    = blk & 7;
  const int rest = blk >> 3;
  const int jblk = rest & 1;
  const int b    = rest >> 1;
  const int tid  = threadIdx.x;
  const int lane = tid & 63;
  const int wv   = tid >> 6;
  const int igrp = lane & 15;
  const int jp   = wv * 4 + (lane >> 4);   // 0..15
  const int j0   = jblk * 32 + jp * 2;
  const int jv   = jblk * 16 + jp;         // v/q dword index (FIX vs R12)
  const int ib   = igrp * 4;
  const int srow_ = tid >> 5;
  const int rtid_ = tid & 31;
  const int t0   = c * CHL;

  float D[9][4][2];
#pragma unroll
  for (int m = 0; m < 9; m++)
#pragma unroll
    for (int ii = 0; ii < 4; ii++) { D[m][ii][0] = 0.f; D[m][ii][1] = 0.f; }

#define ACC8(mm, K0_,K1_,K2_,K3_, Va_, Vb_) {                        \
    D[mm][0][0] += K0_*Va_; D[mm][1][0] += K1_*Va_;                  \
    D[mm][2][0] += K2_*Va_; D[mm][3][0] += K3_*Va_;                  \
    D[mm][0][1] += K0_*Vb_; D[mm][1][1] += K1_*Vb_;                  \
    D[mm][2][1] += K2_*Vb_; D[mm][3][1] += K3_*Vb_; }

#define CSTEP_A(P, R) {                                              \
    const uint32_t* rb = sY + (P) * TILEF_D + (R) * TROW_D;          \
    UNPACK_STEP_COMMON                                               \
    ACC8(0, k00,k01,k02,k03, v0a, v0b);                              \
    switch (i0) {                                                    \
      case 0: ACC8(0, ka0,ka1,ka2,ka3, vaa, vab); break;             \
      case 1: ACC8(1, ka0,ka1,ka2,ka3, vaa, vab); break;             \
      case 2: ACC8(2, ka0,ka1,ka2,ka3, vaa, vab); break;             \
      case 3: ACC8(3, ka0,ka1,ka2,ka3, vaa, vab); break;             \
      case 4: ACC8(4, ka0,ka1,ka2,ka3, vaa, vab); break;             \
      case 5: ACC8(5, ka0,ka1,ka2,ka3, vaa, vab); break;             \
      case 6: ACC8(6, ka0,ka1,ka2,ka3, vaa, vab); break;             \
      default: ACC8(7, ka0,ka1,ka2,ka3, vaa, vab); break;            \
    }                                                                \
    switch (i1) {                                                    \
      case 0: ACC8(0, kb0,kb1,kb2,kb3, vba, vbb); break;             \
      case 1: ACC8(1, kb0,kb1,kb2,kb3, vba, vbb); break;             \
      case 2: ACC8(2, kb0,kb1,kb2,kb3, vba, vbb); break;             \
      case 3: ACC8(3, kb0,kb1,kb2,kb3, vba, vbb); break;             \
      case 4: ACC8(4, kb0,kb1,kb2,kb3, vba, vbb); break;             \
      case 5: ACC8(5, kb0,kb1,kb2,kb3, vba, vbb); break;             \
      case 6: ACC8(6, kb0,kb1,kb2,kb3, vba, vbb); break;             \
      default: ACC8(7, kb0,kb1,kb2,kb3, vba, vbb); break;            \
    } }

  STAGE_TILE(t0, 0);

  for (int tile = 0; tile < NTILE; ++tile) {
    const int p = tile & 1;
    __syncthreads();
#pragma unroll
    for (int r = 0; r < 8; r++) CSTEP_A(p, r);
    if (tile + 1 < NTILE) STAGE_TILE(t0 + (tile + 1) * 8, p ^ 1);
  }
#undef CSTEP_A

  float* dmb = DM + ((int64_t)(c * 32 + b)) * 36864;
#pragma unroll
  for (int m = 0; m < 9; m++)
#pragma unroll
    for (int ii = 0; ii < 4; ii++) {
      dmb[m * 4096 + (ib + ii) * 64 + j0]     = D[m][ii][0];
      dmb[m * 4096 + (ib + ii) * 64 + j0 + 1] = D[m][ii][1];
    }
}

// ---------------- phase B: in-place exclusive prefix (+M0) over chunks ----------------
__global__ void prefix_kernel(const float* __restrict__ M0, float* __restrict__ DM, int nc)
{
  int64_t e = (int64_t)blockIdx.x * blockDim.x + threadIdx.x;
  int b = (int)(e / 36864);
  int r = (int)(e % 36864);
  float run = M0[e];
  for (int cc = 0; cc < nc; cc++) {
    int64_t idx = ((int64_t)(cc * 32 + b)) * 36864 + r;
    float tmp = DM[idx];
    DM[idx] = run;
    run += tmp;
  }
}

// ---------------- phase C: intra-chunk recurrence + readout ----------------
__global__ __launch_bounds__(256) void chunk_scan_kernel(
    const uint32_t* __restrict__ Ypk,
    const float* __restrict__ DM,
    float* __restrict__ out)
{
  __shared__ uint32_t sY[2 * TILEF_D];
  const int blk  = blockIdx.x;
  const int c    = blk & 7;
  const int rest = blk >> 3;
  const int jblk = rest & 1;
  const int b    = rest >> 1;
  const int tid  = threadIdx.x;
  const int lane = tid & 63;
  const int wv   = tid >> 6;
  const int igrp = lane & 15;
  const int jp   = wv * 4 + (lane >> 4);
  const int j0   = jblk * 32 + jp * 2;
  const int jv   = jblk * 16 + jp;         // v dword index (FIX vs R12)
  const int ib   = igrp * 4;
  const int srow_ = tid >> 5;
  const int rtid_ = tid & 31;
  const int t0   = c * CHL;

  float M[9][4][2];
  const float* msb = DM + ((int64_t)(c * 32 + b)) * 36864;
#pragma unroll
  for (int m = 0; m < 9; m++)
#pragma unroll
    for (int ii = 0; ii < 4; ii++) {
      M[m][ii][0] = msb[m * 4096 + (ib + ii) * 64 + j0];
      M[m][ii][1] = msb[m * 4096 + (ib + ii) * 64 + j0 + 1];
    }

#define DO_SLOT(mm, gw, K0_,K1_,K2_,K3_, Va_, Vb_) {                 \
    M[mm][0][0] += K0_*Va_; M[mm][1][0] += K1_*Va_;                  \
    M[mm][2][0] += K2_*Va_; M[mm][3][0] += K3_*Va_;                  \
    M[mm][0][1] += K0_*Vb_; M[mm][1][1] += K1_*Vb_;                  \
    M[mm][2][1] += K2_*Vb_; M[mm][3][1] += K3_*Vb_;                  \
    Mc00 += (gw)*M[mm][0][0]; Mc10 += (gw)*M[mm][1][0];              \
    Mc20 += (gw)*M[mm][2][0]; Mc30 += (gw)*M[mm][3][0];              \
    Mc01 += (gw)*M[mm][0][1]; Mc11 += (gw)*M[mm][1][1];              \
    Mc21 += (gw)*M[mm][2][1]; Mc31 += (gw)*M[mm][3][1]; }

    // routed slot == 0: Mc captured M[0] post-shared-update only; add routed delta
    // unweighted too (reference: all scatter-adds precede readout).
#define DO_SLOT0(gw, K0_,K1_,K2_,K3_, Va_, Vb_) {                    \
    float d00=K0_*Va_, d10=K1_*Va_, d20=K2_*Va_, d30=K3_*Va_;        \
    float d01=K0_*Vb_, d11=K1_*Vb_, d21=K2_*Vb_, d31=K3_*Vb_;        \
    M[0][0][0]+=d00; M[0][1][0]+=d10; M[0][2][0]+=d20; M[0][3][0]+=d30; \
    M[0][0][1]+=d01; M[0][1][1]+=d11; M[0][2][1]+=d21; M[0][3][1]+=d31; \
    Mc00 += d00 + (gw)*M[0][0][0]; Mc10 += d10 + (gw)*M[0][1][0];    \
    Mc20 += d20 + (gw)*M[0][2][0]; Mc30 += d30 + (gw)*M[0][3][0];    \
    Mc01 += d01 + (gw)*M[0][0][1]; Mc11 += d11 + (gw)*M[0][1][1];    \
    Mc21 += d21 + (gw)*M[0][2][1]; Mc31 += d31 + (gw)*M[0][3][1]; }

#define CSTEP_C(P, R, TT) {                                          \
    const uint32_t* rb = sY + (P) * TILEF_D + (R) * TROW_D;          \
    UNPACK_STEP_COMMON                                               \
    uint2 uq = *(const uint2*)(rb + 96 + igrp * 2);                  \
    float q0=bflo(uq.x),q1=bfhi(uq.x),q2=bflo(uq.y),q3=bfhi(uq.y);   \
    const float g0w = gl.z, g1w = gl.w;                              \
    M[0][0][0]+=k00*v0a; M[0][1][0]+=k01*v0a;                        \
    M[0][2][0]+=k02*v0a; M[0][3][0]+=k03*v0a;                        \
    M[0][0][1]+=k00*v0b; M[0][1][1]+=k01*v0b;                        \
    M[0][2][1]+=k02*v0b; M[0][3][1]+=k03*v0b;                        \
    float Mc00=M[0][0][0], Mc10=M[0][1][0], Mc20=M[0][2][0], Mc30=M[0][3][0]; \
    float Mc01=M[0][0][1], Mc11=M[0][1][1], Mc21=M[0][2][1], Mc31=M[0][3][1]; \
    switch (i0) {                                                    \
      case 0: DO_SLOT0(g0w, ka0,ka1,ka2,ka3, vaa, vab); break;       \
      case 1: DO_SLOT(1, g0w, ka0,ka1,ka2,ka3, vaa, vab); break;     \
      case 2: DO_SLOT(2, g0w, ka0,ka1,ka2,ka3, vaa, vab); break;     \
      case 3: DO_SLOT(3, g0w, ka0,ka1,ka2,ka3, vaa, vab); break;     \
      case 4: DO_SLOT(4, g0w, ka0,ka1,ka2,ka3, vaa, vab); break;     \
      case 5: DO_SLOT(5, g0w, ka0,ka1,ka2,ka3, vaa, vab); break;     \
      case 6: DO_SLOT(6, g0w, ka0,ka1,ka2,ka3, vaa, vab); break;     \
      default: DO_SLOT(7, g0w, ka0,ka1,ka2,ka3, vaa, vab); break;    \
    }                                                                \
    switch (i1) {                                                    \
      case 0: DO_SLOT0(g1w, kb0,kb1,kb2,kb3, vba, vbb); break;       \
      case 1: DO_SLOT(1, g1w, kb0,kb1,kb2,kb3, vba, vbb); break;     \
      case 2: DO_SLOT(2, g1w, kb0,kb1,kb2,kb3, vba, vbb); break;     \
      case 3: DO_SLOT(3, g1w, kb0,kb1,kb2,kb3, vba, vbb); break;     \
      case 4: DO_SLOT(4, g1w, kb0,kb1,kb2,kb3, vba, vbb); break;     \
      case 5: DO_SLOT(5, g1w, kb0,kb1,kb2,kb3, vba, vbb); break;     \
      case 6: DO_SLOT(6, g1w, kb0,kb1,kb2,kb3, vba, vbb); break;     \
      default: DO_SLOT(7, g1w, kb0,kb1,kb2,kb3, vba, vbb); break;    \
    }                                                                \
    float p0 = q0*Mc00 + q1*Mc10 + q2*Mc20 + q3*Mc30;                \
    float p1 = q0*Mc01 + q1*Mc11 + q2*Mc21 + q3*Mc31;                \
    p0 = row16_sum(p0); p1 = row16_sum(p1);                          \
    if (igrp == 15) {                                                \
      out[(int64_t)(TT) * (BATCH * HID) + b * HID + j0]     = p0;    \
      out[(int64_t)(TT) * (BATCH * HID) + b * HID + j0 + 1] = p1;    \
    } }

  STAGE_TILE(t0, 0);

  for (int tile = 0; tile < NTILE; ++tile) {
    const int p = tile & 1;
    __syncthreads();
#pragma unroll
    for (int r = 0; r < 8; r++) CSTEP_C(p, r, t0 + tile * 8 + r);
    if (tile + 1 < NTILE) STAGE_TILE(t0 + (tile + 1) * 8, p ^ 1);
  }
#undef CSTEP_C
#undef DO_SLOT
#undef DO_SLOT0

  if (c == 7) {   // last chunk owns M_final
    float* Mf = out + (int64_t)SEQ * BATCH * HID + (int64_t)b * 36864;
#pragma unroll
    for (int m = 0; m < 9; m++)
#pragma unroll
      for (int ii = 0; ii < 4; ii++) {
        Mf[m * 4096 + (ib + ii) * 64 + j0]     = M[m][ii][0];
        Mf[m * 4096 + (ib + ii) * 64 + j0 + 1] = M[m][ii][1];
      }
  }
}

// ---------------- launch ----------------
extern "C" void kernel_launch(void* const* d_in, const int* in_sizes, int n_in,
                              void* d_out, int out_size, void* d_ws, size_t ws_size,
                              hipStream_t stream)
{
  const float* X  = (const float*)d_in[0];
  const float* M0 = (const float*)d_in[1];
  const float* Wk = (const float*)d_in[2];
  const float* bk = (const float*)d_in[3];
  const float* Wv = (const float*)d_in[4];
  const float* bv = (const float*)d_in[5];
  const float* Wg = (const float*)d_in[6];
  const float* bg = (const float*)d_in[7];
  const float* Wq = (const float*)d_in[8];
  const float* bq = (const float*)d_in[9];

  char* ws = (char*)d_ws;
  short*    Xbf  = (short*)(ws + XBF_OFF);
  short*    Wbf  = (short*)(ws + WBF_OFF);
  float*    bb   = (float*)(ws + BB_OFF);
  float4*   gate = (float4*)(ws + GATE_OFF);
  float*    Y    = (float*)(ws + Y_OFF);
  uint32_t* Ypk  = (uint32_t*)(ws + YPK_OFF);  // overlays Xbf (dead after gemm)
  float*    DM   = (float*)(ws + DM_OFF);      // overlays Y   (dead after pack)
  float*    out  = (float*)d_out;

  prep_kernel<<<2048, 256, 0, stream>>>(X, Wk, bk, Wv, bv, Wg, bg, Wq, bq, Xbf, Wbf, bb);
  gate_kernel<<<ROWS / 4, 256, 0, stream>>>(X, Wg, bg, gate);
  dim3 gg(NPAD / 128, ROWS / 128);
  gemm_kernel<<<gg, 256, 0, stream>>>(Xbf, Wbf, bb, Y);
  pack_kernel<<<ROWS / 4, 256, 0, stream>>>(Y, gate, Ypk);
  chunk_accum_kernel<<<32 * NC * 2, 256, 0, stream>>>(Ypk, DM);
  prefix_kernel<<<(32 * 36864) / 256, 256, 0, stream>>>(M0, DM, NC);
  chunk_scan_kernel<<<32 * NC * 2, 256, 0, stream>>>(Ypk, DM, out);
}

// Round 14
// 221.589 us; speedup vs baseline: 1.3290x; 1.1099x over previous
//
#include <hip/hip_runtime.h>
#include <stdint.h>

#define SEQ 256
#define BATCH 32
#define IN_DIM 1024
#define HID 64
#define NPAD 1280
#define ROWS (SEQ*BATCH)   // 8192

// workspace layout (high-water 61,477,888 B — proven footprint):
//  [0,16.78M)   Xbf (prep->gemm) then Ypk bf16-packed (pack->chunks) [8192*928B = 7.6 MB]
//  [16.78M,..)  Wbf, bb, gate
//  [19.53M,61.48M) Y (gemm->pack) then DM (37.75 MB)
#define XBF_OFF   0
#define YPK_OFF   0
#define WBF_OFF   16777216
#define BB_OFF    19398656
#define GATE_OFF  19403776
#define Y_OFF     19534848
#define DM_OFF    19534848

#define NC 8
#define CHL 32      // chunk length
#define NTILE 4     // CHL/8

// packed bf16 record, 232 dwords (928 B)/row:
// ushorts: k0[64]@0 | ka@64 | kb@128 | q@192 | v0@256 | va@320 | vb@384 | gate(4 fp32 raw)@448
// dwords:  k0@0..31 | ka@32 | kb@64 | q@96 | v0@128 | va@160 | vb@192 | gate@224
#define PKROW_D 232
#define TROW_D  232
#define TILEF_D (8*TROW_D)   // 1856 dwords/buffer; x2 = 14,848 B LDS

typedef __attribute__((ext_vector_type(8))) short short8;
typedef __attribute__((ext_vector_type(4))) float floatx4;

typedef const __attribute__((address_space(1))) unsigned int gas_u32;
typedef __attribute__((address_space(3))) unsigned int las_u32;
static __device__ __forceinline__ void gl_lds16(const void* g, void* l) {
  __builtin_amdgcn_global_load_lds((gas_u32*)g, (las_u32*)l, 16, 0, 0);
}

static __device__ __forceinline__ short f2bf(float f) {
  union { float f; uint32_t u; } a; a.f = f;
  uint32_t r = (a.u + 0x7FFFu + ((a.u >> 16) & 1u)) >> 16;  // RNE
  return (short)r;
}
static __device__ __forceinline__ float bflo(uint32_t u){ return __uint_as_float(u << 16); }
static __device__ __forceinline__ float bfhi(uint32_t u){ return __uint_as_float(u & 0xffff0000u); }
static __device__ __forceinline__ float bfu(unsigned short us){ return __uint_as_float(((uint32_t)us) << 16); }

// ---------------- prep ----------------
__global__ void prep_kernel(const float* __restrict__ X,
                            const float* __restrict__ Wk, const float* __restrict__ bk,
                            const float* __restrict__ Wv, const float* __restrict__ bv,
                            const float* __restrict__ Wg, const float* __restrict__ bg,
                            const float* __restrict__ Wq, const float* __restrict__ bq,
                            short* __restrict__ Xbf, short* __restrict__ Wbf,
                            float* __restrict__ bb)
{
  int64_t idx = (int64_t)blockIdx.x * blockDim.x + threadIdx.x;
  int64_t stride = (int64_t)gridDim.x * blockDim.x;
  const int64_t NX4 = (int64_t)ROWS * IN_DIM / 4;
  for (int64_t i = idx; i < NX4; i += stride) {
    float4 x = ((const float4*)X)[i];
    short4 s4;
    s4.x = f2bf(x.x); s4.y = f2bf(x.y); s4.z = f2bf(x.z); s4.w = f2bf(x.w);
    ((short4*)Xbf)[i] = s4;
  }
  const int64_t NW4 = (int64_t)NPAD * IN_DIM / 4;
  for (int64_t i = idx; i < NW4; i += stride) {
    int64_t e = i * 4;
    int r = (int)(e >> 10);
    int k = (int)(e & 1023);
    float4 x;
    if (r < 576)       x = *(const float4*)(Wk + (int64_t)r*1024 + k);
    else if (r < 1152) x = *(const float4*)(Wv + (int64_t)(r-576)*1024 + k);
    else if (r < 1216) x = *(const float4*)(Wq + (int64_t)(r-1152)*1024 + k);
    else               x = make_float4(0.f, 0.f, 0.f, 0.f);
    short4 s4;
    s4.x = f2bf(x.x); s4.y = f2bf(x.y); s4.z = f2bf(x.z); s4.w = f2bf(x.w);
    ((short4*)Wbf)[i] = s4;
  }
  for (int64_t i = idx; i < NPAD; i += stride) {
    int r = (int)i; float v;
    if (r < 576)       v = bk[r];
    else if (r < 1152) v = bv[r - 576];
    else if (r < 1216) v = bq[r - 1152];
    else               v = 0.f;
    bb[r] = v;
  }
}

// ---------------- GEMM ----------------
__global__ __launch_bounds__(256) void gemm_kernel(
    const short* __restrict__ Xbf,
    const short* __restrict__ Wbf,
    const float* __restrict__ bb,
    float* __restrict__ Y)
{
  __shared__ short As[128 * 32];
  __shared__ short Bs[128 * 32];

  const int tid  = threadIdx.x;
  const int lane = tid & 63;
  const int wv   = tid >> 6;
  const int quad = lane >> 4;
  const int cl   = lane & 15;
  const int wm   = wv & 1;
  const int wn   = wv >> 1;
  const int m0 = blockIdx.y * 128;
  const int n0 = blockIdx.x * 128;

  const int srow = wv * 32 + (lane >> 2);
  const int scol = (lane & 3) * 8;
  const short* gA = Xbf + (int64_t)(m0 + srow) * IN_DIM + scol;
  const short* gB = Wbf + (int64_t)(n0 + srow) * IN_DIM + scol;
  short* lA = As + (wv * 32) * 32;
  short* lB = Bs + (wv * 32) * 32;

  floatx4 acc[4][4];
#pragma unroll
  for (int i = 0; i < 4; i++)
#pragma unroll
    for (int k = 0; k < 4; k++) acc[i][k] = (floatx4){0.f, 0.f, 0.f, 0.f};

  for (int ks = 0; ks < IN_DIM; ks += 32) {
    gl_lds16(gA + ks,                lA);
    gl_lds16(gA + 16 * IN_DIM + ks,  lA + 16 * 32);
    gl_lds16(gB + ks,                lB);
    gl_lds16(gB + 16 * IN_DIM + ks,  lB + 16 * 32);
    __syncthreads();

    short8 bfrag[4], afrag[4];
#pragma unroll
    for (int nt = 0; nt < 4; nt++)
      bfrag[nt] = *(const short8*)(&Bs[(wn * 64 + nt * 16 + cl) * 32 + quad * 8]);
#pragma unroll
    for (int mt = 0; mt < 4; mt++)
      afrag[mt] = *(const short8*)(&As[(wm * 64 + mt * 16 + cl) * 32 + quad * 8]);
#pragma unroll
    for (int mt = 0; mt < 4; mt++)
#pragma unroll
      for (int nt = 0; nt < 4; nt++)
        acc[mt][nt] = __builtin_amdgcn_mfma_f32_16x16x32_bf16(afrag[mt], bfrag[nt], acc[mt][nt], 0, 0, 0);
    __syncthreads();
  }

#pragma unroll
  for (int nt = 0; nt < 4; nt++) {
    const int col = n0 + wn * 64 + nt * 16 + cl;
    const float bias = bb[col];
#pragma unroll
    for (int mt = 0; mt < 4; mt++) {
#pragma unroll
      for (int r = 0; r < 4; r++) {
        int row = m0 + wm * 64 + mt * 16 + quad * 4 + r;
        Y[(int64_t)row * NPAD + col] = acc[mt][nt][r] + bias;
      }
    }
  }
}

// ---------------- gate (fp32-exact) ----------------
__global__ __launch_bounds__(256) void gate_kernel(
    const float* __restrict__ X,
    const float* __restrict__ Wg, const float* __restrict__ bg,
    float4* __restrict__ gate)
{
  const int lane = threadIdx.x & 63;
  const int row  = blockIdx.x * 4 + (threadIdx.x >> 6);
  const float* x = X + (int64_t)row * IN_DIM;

  float acc[8];
#pragma unroll
  for (int e = 0; e < 8; e++) acc[e] = 0.f;

#pragma unroll
  for (int i = 0; i < 4; i++) {
    const int off = i * 256 + lane * 4;
    float4 xv = *(const float4*)(x + off);
#pragma unroll
    for (int e = 0; e < 8; e++) {
      float4 wv = *(const float4*)(Wg + e * IN_DIM + off);
      acc[e] += xv.x * wv.x + xv.y * wv.y + xv.z * wv.z + xv.w * wv.w;
    }
  }
#pragma unroll
  for (int e = 0; e < 8; e++) {
#pragma unroll
    for (int m = 32; m >= 1; m >>= 1)
      acc[e] += __shfl_xor(acc[e], m);
    acc[e] += bg[e];
  }

  if (lane == 0) {
    int i0 = 0; float v0 = acc[0];
#pragma unroll
    for (int e = 1; e < 8; e++) if (acc[e] > v0) { v0 = acc[e]; i0 = e; }
    int i1 = -1; float v1 = -3.4e38f;
#pragma unroll
    for (int e = 0; e < 8; e++) if (e != i0 && acc[e] > v1) { v1 = acc[e]; i1 = e; }
    float e1 = __expf(v1 - v0);
    float inv = 1.f / (1.f + e1);
    gate[row] = make_float4(__int_as_float(i0), __int_as_float(i1), inv, e1 * inv);
  }
}

// ---------------- pack: gather + bf16-compress into 928B records ----------------
__global__ __launch_bounds__(256) void pack_kernel(
    const float* __restrict__ Y, const float4* __restrict__ gate,
    uint32_t* __restrict__ Ypk)
{
  const int row  = blockIdx.x * 4 + (threadIdx.x >> 6);
  const int lane = threadIdx.x & 63;
  const float* Yp = Y + (int64_t)row * NPAD;
  uint32_t* Pp = Ypk + (int64_t)row * PKROW_D;
  float4 g = gate[row];
  const int i0 = __float_as_int(g.x), i1 = __float_as_int(g.y);

  if (lane < 56) {
    const int seg = lane >> 3;          // 0:k0 1:ka 2:kb 3:q 4:v0 5:va 6:vb
    const int f0  = (lane & 7) * 8;
    const int slot = (seg == 1 || seg == 5) ? i0 : ((seg == 2 || seg == 6) ? i1 : 0);
    const int base = (seg == 3) ? 1152 : (((seg >= 4) ? 576 : 0) + 64 * slot);
    float4 a = *(const float4*)(Yp + base + f0);
    float4 bq4 = *(const float4*)(Yp + base + f0 + 4);
    short8 s;
    s[0]=f2bf(a.x); s[1]=f2bf(a.y); s[2]=f2bf(a.z); s[3]=f2bf(a.w);
    s[4]=f2bf(bq4.x); s[5]=f2bf(bq4.y); s[6]=f2bf(bq4.z); s[7]=f2bf(bq4.w);
    *(short8*)(Pp + lane * 4) = s;
  } else if (lane == 56) {
    *(float4*)(Pp + 224) = g;           // gate fp32 raw @ dword 224
  }
}

// 16-lane (DPP row) sum; result valid in lane (lane&15)==15.
static __device__ __forceinline__ float row16_sum(float x) {
  float r = x;
  r += __int_as_float(__builtin_amdgcn_update_dpp(0, __float_as_int(r), 0x118, 0xf, 0xf, false));
  r += __int_as_float(__builtin_amdgcn_update_dpp(0, __float_as_int(r), 0x114, 0xf, 0xf, false));
  r += __int_as_float(__builtin_amdgcn_update_dpp(0, __float_as_int(r), 0x112, 0xf, 0xf, false));
  r += __int_as_float(__builtin_amdgcn_update_dpp(0, __float_as_int(r), 0x111, 0xf, 0xf, false));
  return r;
}

// ======================= chunk scan FROM ZERO (R14 restructure) =======================
// Readout is linear in M: M_t = Mstart(c) + M'_t. The local scan (M init 0, the
// proven R13 body incl. DO_SLOT0 dupe semantics) produces o_local AND ΔM=M'_end
// in one pass — chunk_accum is deleted. prefix turns ΔM into Mstart (and writes
// M_final = M0 + Σ ΔM, coalesced). corr_kernel adds q·(Mstart[0]+g0·Mstart[i0]
// +g1·Mstart[i1]) into o (reads slot 0 twice when routed there — exact ref).

#define STAGE_TILE(TBASE, DST) {                                     \
    const int trow = (TBASE) + srow_;                                \
    const uint32_t* Pp = Ypk + (int64_t)(trow * BATCH + b) * PKROW_D;\
    uint32_t* dbuf = sY + (DST) * TILEF_D + srow_ * TROW_D;          \
    _Pragma("unroll")                                                \
    for (int kq = 0; kq < 2; kq++) {                                 \
      const int idx = rtid_ + 32 * kq;                               \
      if (idx < 57)                                                  \
        *(uint4*)(dbuf + idx * 4) = *(const uint4*)(Pp + idx * 4);   \
    } }

#define UNPACK_STEP_COMMON                                           \
    float4 gl = *(const float4*)(rb + 224);                          \
    uint2 uk0 = *(const uint2*)(rb + igrp * 2);                      \
    uint2 uka = *(const uint2*)(rb + 32 + igrp * 2);                 \
    uint2 ukb = *(const uint2*)(rb + 64 + igrp * 2);                 \
    uint32_t pv0 = rb[128 + jv], pva = rb[160 + jv], pvb = rb[192 + jv]; \
    const int i0 = __float_as_int(gl.x);                             \
    const int i1 = __float_as_int(gl.y);                             \
    float k00=bflo(uk0.x),k01=bfhi(uk0.x),k02=bflo(uk0.y),k03=bfhi(uk0.y); \
    float ka0=bflo(uka.x),ka1=bfhi(uka.x),ka2=bflo(uka.y),ka3=bfhi(uka.y); \
    float kb0=bflo(ukb.x),kb1=bfhi(ukb.x),kb2=bflo(ukb.y),kb3=bfhi(ukb.y); \
    float v0a=bflo(pv0), v0b=bfhi(pv0);                              \
    float vaa=bflo(pva), vab=bfhi(pva);                              \
    float vba=bflo(pvb), vbb=bfhi(pvb);

// ---------------- scan: local recurrence from zero; writes o_local and ΔM ----------------
__global__ __launch_bounds__(256) void chunk_scan_kernel(
    const uint32_t* __restrict__ Ypk,
    float* __restrict__ DM,          // OUT: ΔM per (c,b)
    float* __restrict__ out)
{
  __shared__ uint32_t sY[2 * TILEF_D];
  const int blk  = blockIdx.x;
  const int c    = blk & 7;
  const int rest = blk >> 3;
  const int jblk = rest & 1;
  const int b    = rest >> 1;
  const int tid  = threadIdx.x;
  const int lane = tid & 63;
  const int wv   = tid >> 6;
  const int igrp = lane & 15;
  const int jp   = wv * 4 + (lane >> 4);
  const int j0   = jblk * 32 + jp * 2;
  const int jv   = jblk * 16 + jp;         // v/q dword index
  const int ib   = igrp * 4;
  const int srow_ = tid >> 5;
  const int rtid_ = tid & 31;
  const int t0   = c * CHL;

  float M[9][4][2];
#pragma unroll
  for (int m = 0; m < 9; m++)
#pragma unroll
    for (int ii = 0; ii < 4; ii++) { M[m][ii][0] = 0.f; M[m][ii][1] = 0.f; }

#define DO_SLOT(mm, gw, K0_,K1_,K2_,K3_, Va_, Vb_) {                 \
    M[mm][0][0] += K0_*Va_; M[mm][1][0] += K1_*Va_;                  \
    M[mm][2][0] += K2_*Va_; M[mm][3][0] += K3_*Va_;                  \
    M[mm][0][1] += K0_*Vb_; M[mm][1][1] += K1_*Vb_;                  \
    M[mm][2][1] += K2_*Vb_; M[mm][3][1] += K3_*Vb_;                  \
    Mc00 += (gw)*M[mm][0][0]; Mc10 += (gw)*M[mm][1][0];              \
    Mc20 += (gw)*M[mm][2][0]; Mc30 += (gw)*M[mm][3][0];              \
    Mc01 += (gw)*M[mm][0][1]; Mc11 += (gw)*M[mm][1][1];              \
    Mc21 += (gw)*M[mm][2][1]; Mc31 += (gw)*M[mm][3][1]; }

#define DO_SLOT0(gw, K0_,K1_,K2_,K3_, Va_, Vb_) {                    \
    float d00=K0_*Va_, d10=K1_*Va_, d20=K2_*Va_, d30=K3_*Va_;        \
    float d01=K0_*Vb_, d11=K1_*Vb_, d21=K2_*Vb_, d31=K3_*Vb_;        \
    M[0][0][0]+=d00; M[0][1][0]+=d10; M[0][2][0]+=d20; M[0][3][0]+=d30; \
    M[0][0][1]+=d01; M[0][1][1]+=d11; M[0][2][1]+=d21; M[0][3][1]+=d31; \
    Mc00 += d00 + (gw)*M[0][0][0]; Mc10 += d10 + (gw)*M[0][1][0];    \
    Mc20 += d20 + (gw)*M[0][2][0]; Mc30 += d30 + (gw)*M[0][3][0];    \
    Mc01 += d01 + (gw)*M[0][0][1]; Mc11 += d11 + (gw)*M[0][1][1];    \
    Mc21 += d21 + (gw)*M[0][2][1]; Mc31 += d31 + (gw)*M[0][3][1]; }

#define CSTEP_C(P, R, TT) {                                          \
    const uint32_t* rb = sY + (P) * TILEF_D + (R) * TROW_D;          \
    UNPACK_STEP_COMMON                                               \
    uint2 uq = *(const uint2*)(rb + 96 + igrp * 2);                  \
    float q0=bflo(uq.x),q1=bfhi(uq.x),q2=bflo(uq.y),q3=bfhi(uq.y);   \
    const float g0w = gl.z, g1w = gl.w;                              \
    M[0][0][0]+=k00*v0a; M[0][1][0]+=k01*v0a;                        \
    M[0][2][0]+=k02*v0a; M[0][3][0]+=k03*v0a;                        \
    M[0][0][1]+=k00*v0b; M[0][1][1]+=k01*v0b;                        \
    M[0][2][1]+=k02*v0b; M[0][3][1]+=k03*v0b;                        \
    float Mc00=M[0][0][0], Mc10=M[0][1][0], Mc20=M[0][2][0], Mc30=M[0][3][0]; \
    float Mc01=M[0][0][1], Mc11=M[0][1][1], Mc21=M[0][2][1], Mc31=M[0][3][1]; \
    switch (i0) {                                                    \
      case 0: DO_SLOT0(g0w, ka0,ka1,ka2,ka3, vaa, vab); break;       \
      case 1: DO_SLOT(1, g0w, ka0,ka1,ka2,ka3, vaa, vab); break;     \
      case 2: DO_SLOT(2, g0w, ka0,ka1,ka2,ka3, vaa, vab); break;     \
      case 3: DO_SLOT(3, g0w, ka0,ka1,ka2,ka3, vaa, vab); break;     \
      case 4: DO_SLOT(4, g0w, ka0,ka1,ka2,ka3, vaa, vab); break;     \
      case 5: DO_SLOT(5, g0w, ka0,ka1,ka2,ka3, vaa, vab); break;     \
      case 6: DO_SLOT(6, g0w, ka0,ka1,ka2,ka3, vaa, vab); break;     \
      default: DO_SLOT(7, g0w, ka0,ka1,ka2,ka3, vaa, vab); break;    \
    }                                                                \
    switch (i1) {                                                    \
      case 0: DO_SLOT0(g1w, kb0,kb1,kb2,kb3, vba, vbb); break;       \
      case 1: DO_SLOT(1, g1w, kb0,kb1,kb2,kb3, vba, vbb); break;     \
      case 2: DO_SLOT(2, g1w, kb0,kb1,kb2,kb3, vba, vbb); break;     \
      case 3: DO_SLOT(3, g1w, kb0,kb1,kb2,kb3, vba, vbb); break;     \
      case 4: DO_SLOT(4, g1w, kb0,kb1,kb2,kb3, vba, vbb); break;     \
      case 5: DO_SLOT(5, g1w, kb0,kb1,kb2,kb3, vba, vbb); break;     \
      case 6: DO_SLOT(6, g1w, kb0,kb1,kb2,kb3, vba, vbb); break;     \
      default: DO_SLOT(7, g1w, kb0,kb1,kb2,kb3, vba, vbb); break;    \
    }                                                                \
    float p0 = q0*Mc00 + q1*Mc10 + q2*Mc20 + q3*Mc30;                \
    float p1 = q0*Mc01 + q1*Mc11 + q2*Mc21 + q3*Mc31;                \
    p0 = row16_sum(p0); p1 = row16_sum(p1);                          \
    if (igrp == 15) {                                                \
      out[(int64_t)(TT) * (BATCH * HID) + b * HID + j0]     = p0;    \
      out[(int64_t)(TT) * (BATCH * HID) + b * HID + j0 + 1] = p1;    \
    } }

  STAGE_TILE(t0, 0);

  for (int tile = 0; tile < NTILE; ++tile) {
    const int p = tile & 1;
    __syncthreads();
#pragma unroll
    for (int r = 0; r < 8; r++) CSTEP_C(p, r, t0 + tile * 8 + r);
    if (tile + 1 < NTILE) STAGE_TILE(t0 + (tile + 1) * 8, p ^ 1);
  }
#undef CSTEP_C
#undef DO_SLOT
#undef DO_SLOT0

  // ΔM writeout (every chunk)
  float* dmb = DM + ((int64_t)(c * 32 + b)) * 36864;
#pragma unroll
  for (int m = 0; m < 9; m++)
#pragma unroll
    for (int ii = 0; ii < 4; ii++) {
      dmb[m * 4096 + (ib + ii) * 64 + j0]     = M[m][ii][0];
      dmb[m * 4096 + (ib + ii) * 64 + j0 + 1] = M[m][ii][1];
    }
}

// ---------------- prefix: ΔM -> Mstart (exclusive, +M0); writes M_final ----------------
__global__ void prefix_kernel(const float* __restrict__ M0, float* __restrict__ DM,
                              float* __restrict__ out, int nc)
{
  int64_t e = (int64_t)blockIdx.x * blockDim.x + threadIdx.x;   // < 32*36864
  int b = (int)(e / 36864);
  int r = (int)(e % 36864);
  float run = M0[e];
  for (int cc = 0; cc < nc; cc++) {
    int64_t idx = ((int64_t)(cc * 32 + b)) * 36864 + r;
    float tmp = DM[idx];
    DM[idx] = run;
    run += tmp;
  }
  out[(int64_t)SEQ * BATCH * HID + e] = run;   // M_final (same [b][m][i][j] order)
}

// ---------------- corr: o += q·(Mstart[0] + g0·Mstart[i0] + g1·Mstart[i1]) ----------------
// block = (b,c,jh): Mstart j-half staged to LDS as bf16 [m][i][jj] (36.9KB),
// q bf16 (4KB), gates (512B) -> 41.4KB, 3 blocks/CU, 512 blocks = one batch.
__global__ __launch_bounds__(256) void corr_kernel(
    const uint32_t* __restrict__ Ypk, const float4* __restrict__ gate,
    const float* __restrict__ DM, float* __restrict__ out)
{
  __shared__ unsigned short Msb[9 * 64 * 32];   // bf16 Mstart [m][i][jj]
  __shared__ uint32_t qb[32 * 32];              // q bf16 pairs [t][i/2]
  __shared__ float4 gl[32];
  const int blk = blockIdx.x;
  const int c   = blk & 7;
  const int jh  = (blk >> 3) & 1;
  const int b   = blk >> 4;
  const int tid = threadIdx.x;
  const int t0  = c * CHL;

  if (tid < 32) gl[tid] = gate[(t0 + tid) * BATCH + b];
#pragma unroll
  for (int k = 0; k < 4; k++) {
    int f = tid + 256 * k;                // < 1024
    int t = f >> 5, dd = f & 31;
    qb[t * 32 + dd] = Ypk[(int64_t)((t0 + t) * BATCH + b) * PKROW_D + 96 + dd];
  }
  const float* dmb = DM + ((int64_t)(c * 32 + b)) * 36864;
#pragma unroll
  for (int k = 0; k < 36; k++) {
    int f = tid + 256 * k;                // < 9216 float2 units
    int m = f >> 10, r2 = f & 1023, i = r2 >> 4, jp2 = r2 & 15;
    const float2 s = *(const float2*)(dmb + m * 4096 + i * 64 + jh * 32 + jp2 * 2);
    uint32_t d = ((uint32_t)(unsigned short)f2bf(s.x)) |
                 (((uint32_t)(unsigned short)f2bf(s.y)) << 16);
    *((uint32_t*)&Msb[(m * 64 + i) * 32 + jp2 * 2]) = d;
  }
  __syncthreads();

  const int jj = tid & 31;
  const int tg = tid >> 5;
#pragma unroll
  for (int tt = 0; tt < 4; tt++) {
    const int t = tt * 8 + tg;
    float4 g = gl[t];
    const int i0 = __float_as_int(g.x), i1 = __float_as_int(g.y);
    const float g0 = g.z, g1 = g.w;
    float acc = 0.f;
#pragma unroll 8
    for (int i2 = 0; i2 < 32; i2++) {
      uint32_t uq = qb[t * 32 + i2];
      float q0 = bflo(uq), q1 = bfhi(uq);
      int ia = 2 * i2;
      float m0a = bfu(Msb[(0  * 64 + ia) * 32 + jj]);
      float m0b = bfu(Msb[(0  * 64 + ia + 1) * 32 + jj]);
      float maa = bfu(Msb[(i0 * 64 + ia) * 32 + jj]);
      float mab = bfu(Msb[(i0 * 64 + ia + 1) * 32 + jj]);
      float mba = bfu(Msb[(i1 * 64 + ia) * 32 + jj]);
      float mbb = bfu(Msb[(i1 * 64 + ia + 1) * 32 + jj]);
      acc += q0 * (m0a + g0 * maa + g1 * mba);
      acc += q1 * (m0b + g0 * mab + g1 * mbb);
    }
    float* op = out + (int64_t)(t0 + t) * (BATCH * HID) + b * HID + jh * 32 + jj;
    *op += acc;
  }
}

// ---------------- launch ----------------
extern "C" void kernel_launch(void* const* d_in, const int* in_sizes, int n_in,
                              void* d_out, int out_size, void* d_ws, size_t ws_size,
                              hipStream_t stream)
{
  const float* X  = (const float*)d_in[0];
  const float* M0 = (const float*)d_in[1];
  const float* Wk = (const float*)d_in[2];
  const float* bk = (const float*)d_in[3];
  const float* Wv = (const float*)d_in[4];
  const float* bv = (const float*)d_in[5];
  const float* Wg = (const float*)d_in[6];
  const float* bg = (const float*)d_in[7];
  const float* Wq = (const float*)d_in[8];
  const float* bq = (const float*)d_in[9];

  char* ws = (char*)d_ws;
  short*    Xbf  = (short*)(ws + XBF_OFF);
  short*    Wbf  = (short*)(ws + WBF_OFF);
  float*    bb   = (float*)(ws + BB_OFF);
  float4*   gate = (float4*)(ws + GATE_OFF);
  float*    Y    = (float*)(ws + Y_OFF);
  uint32_t* Ypk  = (uint32_t*)(ws + YPK_OFF);  // overlays Xbf (dead after gemm)
  float*    DM   = (float*)(ws + DM_OFF);      // overlays Y   (dead after pack)
  float*    out  = (float*)d_out;

  prep_kernel<<<2048, 256, 0, stream>>>(X, Wk, bk, Wv, bv, Wg, bg, Wq, bq, Xbf, Wbf, bb);
  gate_kernel<<<ROWS / 4, 256, 0, stream>>>(X, Wg, bg, gate);
  dim3 gg(NPAD / 128, ROWS / 128);
  gemm_kernel<<<gg, 256, 0, stream>>>(Xbf, Wbf, bb, Y);
  pack_kernel<<<ROWS / 4, 256, 0, stream>>>(Y, gate, Ypk);
  chunk_scan_kernel<<<32 * NC * 2, 256, 0, stream>>>(Ypk, DM, out);
  prefix_kernel<<<(32 * 36864) / 256, 256, 0, stream>>>(M0, DM, out, NC);
  corr_kernel<<<32 * NC * 2, 256, 0, stream>>>(Ypk, gate, DM, out);
}